// Round 9
// baseline (464.300 us; speedup 1.0000x reference)
//
#include <hip/hip_runtime.h>
#include <hip/hip_bf16.h>

#define NN 50000
#define EE 800000
#define HIDD 128
#define NL 4
#define NC 10
#define BN_EPS 1e-5f
#define EMBBLK 782   // emb blocks inside k_fillemb
#define LBLK 782     // fused-layer grid

typedef __bf16 bf16x8 __attribute__((ext_vector_type(8)));
typedef float f32x4 __attribute__((ext_vector_type(4)));

__device__ __forceinline__ float bf_lo(unsigned int u) { return __uint_as_float(u << 16); }
__device__ __forceinline__ float bf_hi(unsigned int u) { return __uint_as_float(u & 0xFFFF0000u); }

__device__ __forceinline__ int edge_at(const void* ei, int i64, long long idx) {
    return i64 ? (int)((const long long*)ei)[idx] : ((const int*)ei)[idx];
}

__device__ __forceinline__ float flt_at(const void* p, int fp32, size_t idx) {
    return fp32 ? ((const float*)p)[idx] : (float)((const __hip_bfloat16*)p)[idx];
}

// ---------------- setup: detect flags + convert small arrays + pack B + edge pass ----------------
__global__ __launch_bounds__(256) void k_setup(const void* h, const void* ei,
        const void* Wemb, const void* Ws,
        const void* bemb, const void* bs, const void* gam, const void* bet,
        const void* Wm, const void* bm,
        float* bemb_f, float* bs_f, float* gam_f, float* bet_f, float* Wm_f, float* bm_f,
        __bf16* Bhi, __bf16* Blo, int* counts, int* srcs, int* dsts, int* rank,
        int* flags) {
    int b = blockIdx.x, tid = threadIdx.x;
    if (b >= 332) {  // edge pass: self-detect i64, convert, count, record rank
        __shared__ int zeros;
        if (tid == 0) zeros = 0;
        __syncthreads();
        const int* ii = (const int*)ei;
        int lz = 0;
        for (int i = tid; i < 512; i += 256)
            if (ii[2 * i + 1] == 0) lz++;
        if (lz) atomicAdd(&zeros, lz);
        __syncthreads();
        int i64 = (zeros > 256) ? 1 : 0;
        int e = (b - 332) * 256 + tid;
        if (e < EE) {
            int s = edge_at(ei, i64, e);
            int d = edge_at(ei, i64, (long long)EE + e);
            srcs[e] = s;
            dsts[e] = d;
            if ((unsigned)d < NN) rank[e] = atomicAdd(&counts[d], 1);
        }
        return;
    }
    __shared__ int wild, zeros;
    if (tid == 0) { wild = 0; zeros = 0; }
    __syncthreads();
    const unsigned short* hb = (const unsigned short*)h;
    int lw = 0;
    for (int i = tid; i < 4096; i += 256) {
        unsigned short u = hb[i];
        int e = (u >> 7) & 0xFF;
        if ((e >= 0x8F || e == 0) && (u & 0x7FFF) != 0) lw++;
    }
    if (lw) atomicAdd(&wild, lw);
    const int* ii = (const int*)ei;
    int lz = 0;
    for (int i = tid; i < 512; i += 256)
        if (ii[2 * i + 1] == 0) lz++;
    if (lz) atomicAdd(&zeros, lz);
    __syncthreads();
    int fp32 = (wild > 256) ? 1 : 0;
    int i64  = (zeros > 256) ? 1 : 0;
    if (b == 0 && tid == 0) { flags[0] = fp32; flags[1] = i64; }
    if (b < 320) {  // pack 5 weight matrices into MFMA B-fragment order, hi/lo planes
        int idx = b * 256 + tid;  // < 81920
        int m = idx >> 14, r = idx & 16383;
        int kt = r >> 12, nt = (r >> 9) & 7, lane = (r >> 3) & 63, j = r & 7;
        int k = kt * 32 + (lane >> 4) * 8 + j;
        int n = nt * 16 + (lane & 15);
        float w = (m == 0) ? flt_at(Wemb, fp32, (size_t)k * 128 + n)
                           : flt_at(Ws, fp32, (size_t)(m - 1) * 16384 + (size_t)k * 128 + n);
        __bf16 hi = (__bf16)w;
        Bhi[idx] = hi;
        Blo[idx] = (__bf16)(w - (float)hi);
    } else {
        int i = (b - 320) * 256 + tid;
        const void* src; float* dst; int off2;
        if (i < 128)       { src = bemb; dst = bemb_f; off2 = i; }
        else if (i < 640)  { src = bs;   dst = bs_f;   off2 = i - 128; }
        else if (i < 1152) { src = gam;  dst = gam_f;  off2 = i - 640; }
        else if (i < 1664) { src = bet;  dst = bet_f;  off2 = i - 1152; }
        else if (i < 2944) { src = Wm;   dst = Wm_f;   off2 = i - 1664; }
        else if (i < 2954) { src = bm;   dst = bm_f;   off2 = i - 2944; }
        else return;
        dst[off2] = flt_at(src, fp32, off2);
    }
}

// ---------------- merged scan: per-block prefix + co-resident handoff + finalize ----------------
__global__ __launch_bounds__(256) void k_scan(const int* counts, int* offsets, int* bsums,
                                              int* flag, float* dinv, uint2* csrw) {
    __shared__ int sc[256];
    __shared__ int sadd;
    int tid = threadIdx.x;
    int base = blockIdx.x * 1024 + tid * 4;
    int4 d = {0, 0, 0, 0};
    if (base + 3 < NN) {
        int4 c = *(const int4*)(counts + base);
        d.x = c.x + 1; d.y = c.y + 1; d.z = c.z + 1; d.w = c.w + 1;
    } else {
        if (base + 0 < NN) d.x = counts[base] + 1;
        if (base + 1 < NN) d.y = counts[base + 1] + 1;
        if (base + 2 < NN) d.z = counts[base + 2] + 1;
        if (base + 3 < NN) d.w = counts[base + 3] + 1;
    }
    int s = d.x + d.y + d.z + d.w;
    sc[tid] = s;
    __syncthreads();
    for (int off = 1; off < 256; off <<= 1) {
        int v = (tid >= off) ? sc[tid - off] : 0;
        __syncthreads();
        sc[tid] += v;
        __syncthreads();
    }
    int excl = sc[tid] - s;
    if (tid == 255) {
        bsums[blockIdx.x] = sc[255];
        __threadfence();
        __hip_atomic_fetch_add(flag, 1, __ATOMIC_RELEASE, __HIP_MEMORY_SCOPE_AGENT);
    }
    if (tid == 0) {
        long long g = 0;
        while (__hip_atomic_load(flag, __ATOMIC_ACQUIRE, __HIP_MEMORY_SCOPE_AGENT)
               < (int)gridDim.x) {
            __builtin_amdgcn_s_sleep(1);
            if (++g > (1LL << 30)) break;
        }
        int a = 0;
        for (int i = 0; i < (int)blockIdx.x; ++i)
            a += __hip_atomic_load(&bsums[i], __ATOMIC_RELAXED, __HIP_MEMORY_SCOPE_AGENT);
        sadd = a;
    }
    __syncthreads();
    int add = sadd;
    if (base >= NN) return;
    int4 o;
    o.x = excl + add; o.y = o.x + d.x; o.z = o.y + d.y; o.w = o.z + d.z;
    *(int4*)(offsets + base) = o;
    int ov[4] = {o.x, o.y, o.z, o.w};
    int dd[4] = {d.x, d.y, d.z, d.w};
#pragma unroll
    for (int t = 0; t < 4; ++t) {
        int i = base + t;
        if (i < NN) {
            int c = dd[t] - 1;
            float dv = rsqrtf((float)(c + 1));
            dinv[i] = dv;
            csrw[ov[t] + c] = make_uint2((unsigned)i, __float_as_uint(dv * dv));
        }
    }
}

// ---------------- BN affine helpers ----------------
__device__ __forceinline__ void bn_affine(float sm, float sq, float g, float be,
                                          float& S, float& T) {
    float mu = sm * (1.f / NN);
    float var = fmaxf(sq * (1.f / NN) - mu * mu, 0.f);
    S = rsqrtf(var + BN_EPS) * g;
    T = be - mu * S;
}

__device__ __forceinline__ void sum_reps(const float* ST, int cb, float4& sm, float4& sq) {
    sm = make_float4(0.f, 0.f, 0.f, 0.f);
    sq = make_float4(0.f, 0.f, 0.f, 0.f);
#pragma unroll
    for (int rr = 0; rr < 8; ++rr) {
        float4 a = *(const float4*)(ST + rr * 256 + cb);
        float4 b = *(const float4*)(ST + rr * 256 + 128 + cb);
        sm.x += a.x; sm.y += a.y; sm.z += a.z; sm.w += a.w;
        sq.x += b.x; sq.y += b.y; sq.z += b.z; sq.w += b.w;
    }
}

// ---------------- shared MFMA core (64x128 A-tile, 128x128 B, hi/lo split) ----------------
__device__ __forceinline__ void mfma128(const __bf16 a_hi[][136], const __bf16 a_lo[][136],
                                        const __bf16* __restrict__ Bhi,
                                        const __bf16* __restrict__ Blo,
                                        int lane, int rw, int quad, int l15, f32x4* acc) {
#pragma unroll
    for (int nt = 0; nt < 8; ++nt) acc[nt] = (f32x4){0.f, 0.f, 0.f, 0.f};
#pragma unroll
    for (int kt = 0; kt < 4; ++kt) {
        int k0 = kt * 32 + quad * 8;
        bf16x8 ah = *(const bf16x8*)&a_hi[rw + l15][k0];
        bf16x8 al = *(const bf16x8*)&a_lo[rw + l15][k0];
#pragma unroll
        for (int nt = 0; nt < 8; ++nt) {
            size_t boff = (((size_t)(kt * 8 + nt) * 64 + lane) * 8);
            bf16x8 bh = *(const bf16x8*)(Bhi + boff);
            bf16x8 bl = *(const bf16x8*)(Blo + boff);
            acc[nt] = __builtin_amdgcn_mfma_f32_16x16x32_bf16(ah, bh, acc[nt], 0, 0, 0);
            acc[nt] = __builtin_amdgcn_mfma_f32_16x16x32_bf16(al, bh, acc[nt], 0, 0, 0);
            acc[nt] = __builtin_amdgcn_mfma_f32_16x16x32_bf16(ah, bl, acc[nt], 0, 0, 0);
        }
    }
}

__device__ __forceinline__ void stage_acc(float Cs[][132], const f32x4* acc,
                                          int rw, int quad, int l15) {
#pragma unroll
    for (int nt = 0; nt < 8; ++nt) {
        int col = nt * 16 + l15;
#pragma unroll
        for (int reg = 0; reg < 4; ++reg)
            Cs[rw + quad * 4 + reg][col] = acc[nt][reg];
    }
}

// ---------------- merged fill + embedding GEMM ----------------
__global__ __launch_bounds__(256) void k_fillemb(const void* __restrict__ Araw,
        const __bf16* __restrict__ Bhi, const __bf16* __restrict__ Blo,
        const float* __restrict__ bias, float* __restrict__ C,
        unsigned short* __restrict__ Cb, const int* __restrict__ flags,
        const int* __restrict__ srcs, const int* __restrict__ dsts,
        const int* __restrict__ rank, const int* __restrict__ offsets,
        const float* __restrict__ dinv, uint2* __restrict__ csrw) {
    int tid = threadIdx.x;
    if (blockIdx.x >= EMBBLK) {   // ---- fill part ----
        int e = (blockIdx.x - EMBBLK) * 256 + tid;
        if (e >= EE) return;
        int d = dsts[e];
        if ((unsigned)d >= NN) return;
        int s = srcs[e];
        if ((unsigned)s >= NN) s = d;
        int r = rank[e];
        float w = dinv[s] * dinv[d];
        csrw[offsets[d] + r] = make_uint2((unsigned)s, __float_as_uint(w));
        return;
    }
    __shared__ __align__(16) char smem[2 * 64 * 136 * 2];
    __bf16 (*a_hi)[136] = (__bf16(*)[136])smem;
    __bf16 (*a_lo)[136] = (__bf16(*)[136])(smem + 64 * 136 * 2);
    float (*Cs)[132] = (float(*)[132])smem;
    int r0 = blockIdx.x * 64;
    int cq = tid & 31, rb = tid >> 5, cb4 = cq * 4;
    int afp32 = flags[0];
#pragma unroll
    for (int p = 0; p < 8; ++p) {
        int r = rb + p * 8;
        int gr = r0 + r;
        float f[4] = {0.f, 0.f, 0.f, 0.f};
        if (gr < NN) {
            if (afp32) {
                float4 v = ((const float4*)Araw)[(size_t)gr * 32 + cq];
                f[0] = v.x; f[1] = v.y; f[2] = v.z; f[3] = v.w;
            } else {
                const __hip_bfloat16* ab = (const __hip_bfloat16*)Araw + (size_t)gr * 128 + cb4;
#pragma unroll
                for (int t = 0; t < 4; ++t) f[t] = (float)ab[t];
            }
        }
        union { __bf16 b[4]; ushort4 u; } ph, pl;
#pragma unroll
        for (int t = 0; t < 4; ++t) {
            __bf16 hi = (__bf16)f[t];
            ph.b[t] = hi;
            pl.b[t] = (__bf16)(f[t] - (float)hi);
        }
        *(ushort4*)&a_hi[r][cb4] = ph.u;
        *(ushort4*)&a_lo[r][cb4] = pl.u;
    }
    __syncthreads();
    int lane = tid & 63, wave = tid >> 6, quad = lane >> 4, l15 = lane & 15, rw = wave * 16;
    f32x4 acc[8];
    mfma128(a_hi, a_lo, Bhi, Blo, lane, rw, quad, l15, acc);     // W_emb
    __syncthreads();
    stage_acc(Cs, acc, rw, quad, l15);
    __syncthreads();
    int colc = (tid & 15) * 8;
    float4 b0v = *(const float4*)(bias + colc);
    float4 b1v = *(const float4*)(bias + colc + 4);
    float v[4][8];
#pragma unroll
    for (int p = 0; p < 4; ++p) {
        int row = (tid >> 4) + p * 16;
        *(float4*)&v[p][0] = *(const float4*)&Cs[row][colc];
        *(float4*)&v[p][4] = *(const float4*)&Cs[row][colc + 4];
        v[p][0] += b0v.x; v[p][1] += b0v.y; v[p][2] += b0v.z; v[p][3] += b0v.w;
        v[p][4] += b1v.x; v[p][5] += b1v.y; v[p][6] += b1v.z; v[p][7] += b1v.w;
        int gr = r0 + row;
        if (gr < NN) {
            float* cr = C + (size_t)gr * 128 + colc;
            *(float4*)cr = *(float4*)&v[p][0];
            *(float4*)(cr + 4) = *(float4*)&v[p][4];
        }
    }
    __syncthreads();
#pragma unroll
    for (int p = 0; p < 4; ++p) {
        int row = (tid >> 4) + p * 16;
        union { __bf16 b[8]; uint4 u; } ph, pl;
#pragma unroll
        for (int t = 0; t < 8; ++t) {
            float x = v[p][t];
            __bf16 hi = (__bf16)x;
            ph.b[t] = hi;
            pl.b[t] = (__bf16)(x - (float)hi);
        }
        *(uint4*)&a_hi[row][colc] = ph.u;
        *(uint4*)&a_lo[row][colc] = pl.u;
    }
    __syncthreads();
    mfma128(a_hi, a_lo, Bhi + 16384, Blo + 16384, lane, rw, quad, l15, acc);  // W_0
    __syncthreads();
    stage_acc(Cs, acc, rw, quad, l15);
    __syncthreads();
#pragma unroll
    for (int p = 0; p < 4; ++p) {
        int row = (tid >> 4) + p * 16;
        int gr = r0 + row;
        if (gr >= NN) continue;
        float w[8];
        *(float4*)&w[0] = *(const float4*)&Cs[row][colc];
        *(float4*)&w[4] = *(const float4*)&Cs[row][colc + 4];
        union { unsigned short us[8]; uint4 u4; } pk;
#pragma unroll
        for (int t = 0; t < 8; ++t)
            pk.us[t] = __bfloat16_as_ushort(__float2bfloat16(w[t]));
        *(uint4*)(Cb + (size_t)gr * 128 + colc) = pk.u4;
    }
}

#define FMA8(A, U, W) \
    A[0] = fmaf(bf_lo(U.x), W, A[0]); A[1] = fmaf(bf_hi(U.x), W, A[1]); \
    A[2] = fmaf(bf_lo(U.y), W, A[2]); A[3] = fmaf(bf_hi(U.y), W, A[3]); \
    A[4] = fmaf(bf_lo(U.z), W, A[4]); A[5] = fmaf(bf_hi(U.z), W, A[5]); \
    A[6] = fmaf(bf_lo(U.w), W, A[6]); A[7] = fmaf(bf_hi(U.w), W, A[7]);

// ---------------- fused layer (round-5 proven structure, two fixes) ----------------
// Fix 1: two-level barrier arrive (8 strided group counters + 1 global) — round 5's
//        single-address arrive serialized 782 device atomics (~25 us/barrier).
// Fix 2: phase-A inner gather = round-1's measured-fastest shape (2-deep, j+=8).
// Co-residency: __launch_bounds__(256,4) => 4 blocks/CU => 1024 slots >= 782; LDS
// 37888 B => 4x37888 = 151552 <= 163840. Host occupancy check gates this path.
__global__ __launch_bounds__(256, 4) void k_layer(
        const unsigned int* __restrict__ xb,
        const uint2* __restrict__ csrw,
        const int* __restrict__ offsets,
        const int* __restrict__ counts,
        const float* __restrict__ bias,
        float* __restrict__ stats,
        const float* __restrict__ gamma,
        const float* __restrict__ beta,
        float* __restrict__ hbuf,
        const __bf16* __restrict__ Bhi,
        const __bf16* __restrict__ Blo,
        unsigned short* __restrict__ xbout,
        const float* __restrict__ Wm,
        const float* __restrict__ bm,
        void* __restrict__ out,
        const int* __restrict__ flags,
        int mode, int* bar) {
    __shared__ __align__(16) char smem[37888];
    float (*agg)[132] = (float(*)[132])smem;       // 33792 B
    float* red = (float*)(smem + 33792);           // 4096 B (phase A scratch)
    int tid = threadIdx.x;
    int wave = tid >> 6, lane = tid & 63;
    int l15 = lane & 15, quarter = lane >> 4;
    int r0 = blockIdx.x * 64;
    int col = l15 * 8;
    // ---------------- phase A: aggregate 16 nodes per wave into LDS ----------------
    float4 b0 = *(const float4*)(bias + col);
    float4 b1 = *(const float4*)(bias + col + 4);
    float ssm[8] = {0.f, 0.f, 0.f, 0.f, 0.f, 0.f, 0.f, 0.f};
    float ssq[8] = {0.f, 0.f, 0.f, 0.f, 0.f, 0.f, 0.f, 0.f};
    int nb0 = r0 + wave * 16;
    int nm = nb0 + l15;
    int offs = 0, cnts0 = 0;
    if (nm < NN) { offs = offsets[nm]; cnts0 = counts[nm]; }
    int st_n = __shfl(offs, 0), cn_n = __shfl(cnts0, 0) + 1;
    uint2 rec = make_uint2(0u, 0u);
    if (lane < cn_n) rec = csrw[st_n + lane];
#pragma unroll 1
    for (int i = 0; i < 16; ++i) {
        int node = nb0 + i;
        int stc = st_n, cnc = cn_n;
        uint2 cur = rec;
        if (i < 15) {   // prefetch next node's records
            st_n = __shfl(offs, i + 1);
            cn_n = __shfl(cnts0, i + 1) + 1;
            rec = make_uint2(0u, 0u);
            if (lane < cn_n) rec = csrw[st_n + lane];
        }
        if (node >= NN) continue;
        int sidx = (int)cur.x;
        float wl = __uint_as_float(cur.y);
        float a0[8] = {0.f, 0.f, 0.f, 0.f, 0.f, 0.f, 0.f, 0.f};
        float a1[8] = {0.f, 0.f, 0.f, 0.f, 0.f, 0.f, 0.f, 0.f};
        int base = 0;
        for (;;) {
            int m = min(64, cnc - base);
            int j = 0;
            for (; j + 4 < m; j += 8) {   // 2 gathers in flight (8 edges) — round-1 shape
                int e0 = j + quarter, e1 = j + 4 + quarter;
                int s0 = __shfl(sidx, e0); float w0 = __shfl(wl, e0);
                int s1 = __shfl(sidx, e1); float w1 = __shfl(wl, e1);
                uint4 u0 = *((const uint4*)(xb + (size_t)s0 * 64) + l15);
                uint4 u1 = *((const uint4*)(xb + (size_t)s1 * 64) + l15);
                FMA8(a0, u0, w0);
                FMA8(a1, u1, w1);
            }
            if (j < m) {                  // <=4 edges remain (w=0 masking)
                int e0 = j + quarter;
                int s0 = __shfl(sidx, e0); float w0 = __shfl(wl, e0);
                uint4 u0 = *((const uint4*)(xb + (size_t)s0 * 64) + l15);
                FMA8(a0, u0, w0);
            }
            base += 64;
            if (base >= cnc) break;
            uint2 r2 = make_uint2(0u, 0u);
            if (base + lane < cnc) r2 = csrw[stc + base + lane];
            sidx = (int)r2.x;
            wl = __uint_as_float(r2.y);
        }
#pragma unroll
        for (int k = 0; k < 8; ++k) {
            float a = a0[k] + a1[k];
            a += __shfl_xor(a, 16);
            a += __shfl_xor(a, 32);
            a0[k] = a;
        }
        if (quarter == 0) {
            float o[8];
            o[0] = a0[0] + b0.x; o[1] = a0[1] + b0.y;
            o[2] = a0[2] + b0.z; o[3] = a0[3] + b0.w;
            o[4] = a0[4] + b1.x; o[5] = a0[5] + b1.y;
            o[6] = a0[6] + b1.z; o[7] = a0[7] + b1.w;
            int row = wave * 16 + i;
            *(float4*)&agg[row][col] = *(float4*)&o[0];
            *(float4*)&agg[row][col + 4] = *(float4*)&o[4];
#pragma unroll
            for (int k = 0; k < 8; ++k) {
                ssm[k] += o[k];
                ssq[k] = fmaf(o[k], o[k], ssq[k]);
            }
        }
    }
    if (quarter == 0) {
#pragma unroll
        for (int k = 0; k < 8; ++k) {
            red[wave * 256 + col + k] = ssm[k];
            red[wave * 256 + 128 + col + k] = ssq[k];
        }
    }
    __syncthreads();
    float vsum = red[tid] + red[256 + tid] + red[512 + tid] + red[768 + tid];
    atomicAdd(&stats[(blockIdx.x & 7) * 256 + tid], vsum);
    // ---------------- two-level device barrier ----------------
    __syncthreads();
    if (tid == 0) {
        __threadfence();
        int g2 = blockIdx.x & 7;
        int cg = (int)((gridDim.x - g2 + 7) >> 3);   // blocks in this group
        int prev = __hip_atomic_fetch_add(&bar[(1 + g2) * 16], 1,
                                          __ATOMIC_ACQ_REL, __HIP_MEMORY_SCOPE_AGENT);
        if (prev == cg - 1)
            __hip_atomic_fetch_add(&bar[0], 1, __ATOMIC_ACQ_REL, __HIP_MEMORY_SCOPE_AGENT);
        long long gd = 0;
        while (__hip_atomic_load(&bar[0], __ATOMIC_ACQUIRE, __HIP_MEMORY_SCOPE_AGENT) < 8) {
            __builtin_amdgcn_s_sleep(2);
            if (++gd > (1LL << 22)) break;   // safety valve: degrade, never hang
        }
    }
    __syncthreads();
    // stage stats into LDS via device-scope loads (bypass possibly-stale XCD L2)
    float* stbuf = (float*)(smem + 33792);   // red is dead
    {
        float s = 0.f;
#pragma unroll
        for (int rp = 0; rp < 8; ++rp)
            s += __hip_atomic_load(&stats[rp * 256 + tid], __ATOMIC_RELAXED,
                                   __HIP_MEMORY_SCOPE_AGENT);
        stbuf[tid] = s;
    }
    __syncthreads();
    // ---------------- phase B ----------------
    if (mode == 0) {
        __bf16 (*a_hi)[136] = (__bf16(*)[136])smem;
        __bf16 (*a_lo)[136] = (__bf16(*)[136])(smem + 64 * 136 * 2);
        float (*Cs)[132] = (float(*)[132])smem;
        int cq = tid & 31, rb = tid >> 5, cb4 = cq * 4;
        float4 S4, T4;
        {
            float4 sm = *(const float4*)&stbuf[cb4];
            float4 sq = *(const float4*)&stbuf[128 + cb4];
            float4 g  = *(const float4*)(gamma + cb4);
            float4 be = *(const float4*)(beta + cb4);
            bn_affine(sm.x, sq.x, g.x, be.x, S4.x, T4.x);
            bn_affine(sm.y, sq.y, g.y, be.y, S4.y, T4.y);
            bn_affine(sm.z, sq.z, g.z, be.z, S4.z, T4.z);
            bn_affine(sm.w, sq.w, g.w, be.w, S4.w, T4.w);
        }
        float fv[8][4];
#pragma unroll
        for (int p = 0; p < 8; ++p) {
            int r = rb + p * 8;
            int gr = r0 + r;
            fv[p][0] = fv[p][1] = fv[p][2] = fv[p][3] = 0.f;
            if (gr < NN) {
                float4 v = *(const float4*)(hbuf + (size_t)gr * 128 + cb4);
                float4 a = *(const float4*)&agg[r][cb4];
                v.x += fmaxf(fmaf(a.x, S4.x, T4.x), 0.f);
                v.y += fmaxf(fmaf(a.y, S4.y, T4.y), 0.f);
                v.z += fmaxf(fmaf(a.z, S4.z, T4.z), 0.f);
                v.w += fmaxf(fmaf(a.w, S4.w, T4.w), 0.f);
                *(float4*)(hbuf + (size_t)gr * 128 + cb4) = v;   // in-place residual
                fv[p][0] = v.x; fv[p][1] = v.y; fv[p][2] = v.z; fv[p][3] = v.w;
            }
        }
        __syncthreads();   // agg + stbuf reads done before frags overwrite smem
#pragma unroll
        for (int p = 0; p < 8; ++p) {
            int r = rb + p * 8;
            union { __bf16 b[4]; ushort4 u; } ph, pl;
#pragma unroll
            for (int t = 0; t < 4; ++t) {
                __bf16 hi = (__bf16)fv[p][t];
                ph.b[t] = hi;
                pl.b[t] = (__bf16)(fv[p][t] - (float)hi);
            }
            *(ushort4*)&a_hi[r][cb4] = ph.u;
            *(ushort4*)&a_lo[r][cb4] = pl.u;
        }
        __syncthreads();
        f32x4 acc[8];
        mfma128(a_hi, a_lo, Bhi, Blo, lane, wave * 16, quarter, l15, acc);
        __syncthreads();
        stage_acc(Cs, acc, wave * 16, quarter, l15);
        __syncthreads();
        int colc = (tid & 15) * 8;
#pragma unroll
        for (int p = 0; p < 4; ++p) {
            int row = (tid >> 4) + p * 16;
            int gr = r0 + row;
            if (gr >= NN) continue;
            float w[8];
            *(float4*)&w[0] = *(const float4*)&Cs[row][colc];
            *(float4*)&w[4] = *(const float4*)&Cs[row][colc + 4];
            union { unsigned short us[8]; uint4 u4; } pk;
#pragma unroll
            for (int t = 0; t < 8; ++t)
                pk.us[t] = __bfloat16_as_ushort(__float2bfloat16(w[t]));
            *(uint4*)(xbout + (size_t)gr * 128 + colc) = pk.u4;
        }
    } else {
        // final layer: BN + relu + residual -> MLP (weights via broadcast global reads)
        int c = l15;
        float S[8], T[8];
#pragma unroll
        for (int q = 0; q < 2; ++q) {
            float4 sm = *(const float4*)&stbuf[c * 8 + q * 4];
            float4 sq = *(const float4*)&stbuf[128 + c * 8 + q * 4];
            float4 g  = *(const float4*)(gamma + c * 8 + q * 4);
            float4 be = *(const float4*)(beta + c * 8 + q * 4);
            bn_affine(sm.x, sq.x, g.x, be.x, S[q * 4 + 0], T[q * 4 + 0]);
            bn_affine(sm.y, sq.y, g.y, be.y, S[q * 4 + 1], T[q * 4 + 1]);
            bn_affine(sm.z, sq.z, g.z, be.z, S[q * 4 + 2], T[q * 4 + 2]);
            bn_affine(sm.w, sq.w, g.w, be.w, S[q * 4 + 3], T[q * 4 + 3]);
        }
        int fp32o = flags[0];
#pragma unroll 1
        for (int chunk = 0; chunk < 4; ++chunk) {
            int row = wave * 16 + chunk * 4 + quarter;
            int node = r0 + row;
            if (node >= NN) continue;   // uniform within the 16-lane group
            size_t rowo = (size_t)node * 128 + c * 8;
            float4 h0 = *(const float4*)(hbuf + rowo);
            float4 h1 = *(const float4*)(hbuf + rowo + 4);
            float4 a0v = *(const float4*)&agg[row][c * 8];
            float4 a1v = *(const float4*)&agg[row][c * 8 + 4];
            float hv[8];
            hv[0] = h0.x + fmaxf(fmaf(a0v.x, S[0], T[0]), 0.f);
            hv[1] = h0.y + fmaxf(fmaf(a0v.y, S[1], T[1]), 0.f);
            hv[2] = h0.z + fmaxf(fmaf(a0v.z, S[2], T[2]), 0.f);
            hv[3] = h0.w + fmaxf(fmaf(a0v.w, S[3], T[3]), 0.f);
            hv[4] = h1.x + fmaxf(fmaf(a1v.x, S[4], T[4]), 0.f);
            hv[5] = h1.y + fmaxf(fmaf(a1v.y, S[5], T[5]), 0.f);
            hv[6] = h1.z + fmaxf(fmaf(a1v.z, S[6], T[6]), 0.f);
            hv[7] = h1.w + fmaxf(fmaf(a1v.w, S[7], T[7]), 0.f);
            float p[10];
#pragma unroll
            for (int cls = 0; cls < 10; ++cls) p[cls] = 0.f;
#pragma unroll
            for (int t = 0; t < 8; ++t) {
                const float* wr = Wm + (size_t)(c * 8 + t) * 10;
#pragma unroll
                for (int cls = 0; cls < 10; ++cls)
                    p[cls] = fmaf(hv[t], wr[cls], p[cls]);
            }
#pragma unroll
            for (int m = 1; m < 16; m <<= 1)
#pragma unroll
                for (int cls = 0; cls < 10; ++cls)
                    p[cls] += __shfl_xor(p[cls], m);
            if (c == 0) {
                if (fp32o) {
                    float* o = (float*)out;
                    for (int cls = 0; cls < 10; ++cls) o[node * 10 + cls] = p[cls] + bm[cls];
                } else {
                    __hip_bfloat16* o = (__hip_bfloat16*)out;
                    for (int cls = 0; cls < 10; ++cls)
                        o[node * 10 + cls] = __float2bfloat16(p[cls] + bm[cls]);
                }
            }
        }
    }
}

// ---------------- fallback path (unfused, round-1 agg shape) ----------------
__global__ __launch_bounds__(256) void k_agg(const unsigned int* __restrict__ xb,
                                             const uint2* __restrict__ csrw,
                                             const int* __restrict__ offsets,
                                             const int* __restrict__ counts,
                                             const float* __restrict__ bias,
                                             float* __restrict__ out,
                                             float* __restrict__ stats) {
    int tid = threadIdx.x;
    int wave = tid >> 6, lane = tid & 63;
    int l15 = lane & 15, quarter = lane >> 4;
    int col = l15 * 8;
    int node = blockIdx.x * 4 + wave;
    float4 b0 = *(const float4*)(bias + col);
    float4 b1 = *(const float4*)(bias + col + 4);
    int start = offsets[node];
    int cnt = counts[node] + 1;
    uint2 rec = make_uint2(0u, 0u);
    if (lane < cnt) rec = csrw[start + lane];
    int sidx = (int)rec.x;
    float wl = __uint_as_float(rec.y);
    float a0[8] = {0.f, 0.f, 0.f, 0.f, 0.f, 0.f, 0.f, 0.f};
    float a1[8] = {0.f, 0.f, 0.f, 0.f, 0.f, 0.f, 0.f, 0.f};
    int base = 0;
    for (;;) {
        int m = min(64, cnt - base);
        int j = 0;
        for (; j + 4 < m; j += 8) {
            int e0 = j + quarter, e1 = j + 4 + quarter;
            int s0 = __shfl(sidx, e0); float w0 = __shfl(wl, e0);
            int s1 = __shfl(sidx, e1); float w1 = __shfl(wl, e1);
            uint4 u0 = *((const uint4*)(xb + (size_t)s0 * 64) + l15);
            uint4 u1 = *((const uint4*)(xb + (size_t)s1 * 64) + l15);
            FMA8(a0, u0, w0);
            FMA8(a1, u1, w1);
        }
        if (j < m) {
            int e0 = j + quarter;
            int s0 = __shfl(sidx, e0); float w0 = __shfl(wl, e0);
            uint4 u0 = *((const uint4*)(xb + (size_t)s0 * 64) + l15);
            FMA8(a0, u0, w0);
        }
        base += 64;
        if (base >= cnt) break;
        uint2 r = make_uint2(0u, 0u);
        if (base + lane < cnt) r = csrw[start + base + lane];
        sidx = (int)r.x;
        wl = __uint_as_float(r.y);
    }
#pragma unroll
    for (int k = 0; k < 8; ++k) {
        float a = a0[k] + a1[k];
        a += __shfl_xor(a, 16);
        a += __shfl_xor(a, 32);
        a0[k] = a;
    }
    __shared__ float red[4][256];
    if (quarter == 0) {
        float o[8];
        o[0] = a0[0] + b0.x; o[1] = a0[1] + b0.y;
        o[2] = a0[2] + b0.z; o[3] = a0[3] + b0.w;
        o[4] = a0[4] + b1.x; o[5] = a0[5] + b1.y;
        o[6] = a0[6] + b1.z; o[7] = a0[7] + b1.w;
        float* orow = out + (size_t)node * 128 + col;
        *(float4*)orow = *(float4*)&o[0];
        *(float4*)(orow + 4) = *(float4*)&o[4];
#pragma unroll
        for (int k = 0; k < 8; ++k) {
            red[wave][col + k] = o[k];
            red[wave][128 + col + k] = o[k] * o[k];
        }
    }
    __syncthreads();
    float v = red[0][tid] + red[1][tid] + red[2][tid] + red[3][tid];
    atomicAdd(&stats[(blockIdx.x & 7) * 256 + tid], v);
}

__global__ __launch_bounds__(256) void k_gemm_layer(const float* __restrict__ Ah,
                                                    const float* __restrict__ Aagg,
                                                    const float* __restrict__ ST,
                                                    const float* __restrict__ gamma,
                                                    const float* __restrict__ beta,
                                                    const __bf16* __restrict__ Bhi,
                                                    const __bf16* __restrict__ Blo,
                                                    unsigned short* __restrict__ Cb,
                                                    float* __restrict__ Hout, int M) {
    __shared__ __align__(16) char smem[2 * 64 * 136 * 2];
    __bf16 (*a_hi)[136] = (__bf16(*)[136])smem;
    __bf16 (*a_lo)[136] = (__bf16(*)[136])(smem + 64 * 136 * 2);
    float (*Cs)[132] = (float(*)[132])smem;
    int tid = threadIdx.x;
    int r0 = blockIdx.x * 64;
    int cq = tid & 31, rb = tid >> 5, cb4 = cq * 4;
    float4 S4, T4;
    {
        float4 sm, sq;
        sum_reps(ST, cb4, sm, sq);
        float4 g  = *(const float4*)(gamma + cb4);
        float4 be = *(const float4*)(beta + cb4);
        bn_affine(sm.x, sq.x, g.x, be.x, S4.x, T4.x);
        bn_affine(sm.y, sq.y, g.y, be.y, S4.y, T4.y);
        bn_affine(sm.z, sq.z, g.z, be.z, S4.z, T4.z);
        bn_affine(sm.w, sq.w, g.w, be.w, S4.w, T4.w);
    }
#pragma unroll
    for (int p = 0; p < 8; ++p) {
        int r = rb + p * 8;
        int gr = r0 + r;
        float f[4] = {0.f, 0.f, 0.f, 0.f};
        if (gr < M) {
            float4 v = *(const float4*)(Ah + (size_t)gr * 128 + cb4);
            float4 a = *(const float4*)(Aagg + (size_t)gr * 128 + cb4);
            v.x += fmaxf(fmaf(a.x, S4.x, T4.x), 0.f);
            v.y += fmaxf(fmaf(a.y, S4.y, T4.y), 0.f);
            v.z += fmaxf(fmaf(a.z, S4.z, T4.z), 0.f);
            v.w += fmaxf(fmaf(a.w, S4.w, T4.w), 0.f);
            *(float4*)(Hout + (size_t)gr * 128 + cb4) = v;
            f[0] = v.x; f[1] = v.y; f[2] = v.z; f[3] = v.w;
        }
        union { __bf16 b[4]; ushort4 u; } ph, pl;
#pragma unroll
        for (int t = 0; t < 4; ++t) {
            __bf16 hi = (__bf16)f[t];
            ph.b[t] = hi;
            pl.b[t] = (__bf16)(f[t] - (float)hi);
        }
        *(ushort4*)&a_hi[r][cb4] = ph.u;
        *(ushort4*)&a_lo[r][cb4] = pl.u;
    }
    __syncthreads();
    int lane = tid & 63, wave = tid >> 6, quad = lane >> 4, l15 = lane & 15, rw = wave * 16;
    f32x4 acc[8];
    mfma128(a_hi, a_lo, Bhi, Blo, lane, rw, quad, l15, acc);
    __syncthreads();
    stage_acc(Cs, acc, rw, quad, l15);
    __syncthreads();
    int colc = (tid & 15) * 8;
#pragma unroll
    for (int p = 0; p < 4; ++p) {
        int row = (tid >> 4) + p * 16;
        int gr = r0 + row;
        if (gr >= M) continue;
        float w[8];
        *(float4*)&w[0] = *(const float4*)&Cs[row][colc];
        *(float4*)&w[4] = *(const float4*)&Cs[row][colc + 4];
        union { unsigned short us[8]; uint4 u4; } pk;
#pragma unroll
        for (int t = 0; t < 8; ++t)
            pk.us[t] = __bfloat16_as_ushort(__float2bfloat16(w[t]));
        *(uint4*)(Cb + (size_t)gr * 128 + colc) = pk.u4;
    }
}

__global__ __launch_bounds__(256) void k_mlp_fused(const float* __restrict__ h,
                                                   const float* __restrict__ agg,
                                                   const float* __restrict__ ST,
                                                   const float* __restrict__ gamma,
                                                   const float* __restrict__ beta,
                                                   const float* __restrict__ Wm,
                                                   const float* __restrict__ bm,
                                                   void* __restrict__ out,
                                                   const int* __restrict__ flags) {
    __shared__ float Wt[10][132];
    int tid = threadIdx.x;
    for (int i = tid; i < 1280; i += 256) {
        int cls = i >> 7, k = i & 127;
        Wt[cls][k] = Wm[k * 10 + cls];
    }
    __syncthreads();
    int wave = tid >> 6, lane = tid & 63;
    int nl = lane >> 4, c = lane & 15;
    int node = blockIdx.x * 16 + wave * 4 + nl;
    size_t rowo = (size_t)node * 128 + c * 8;
    float4 h0 = *(const float4*)(h + rowo);
    float4 h1 = *(const float4*)(h + rowo + 4);
    float4 a0 = *(const float4*)(agg + rowo);
    float4 a1 = *(const float4*)(agg + rowo + 4);
    float S[8], T[8];
#pragma unroll
    for (int q = 0; q < 2; ++q) {
        float4 sm, sq;
        sum_reps(ST, c * 8 + q * 4, sm, sq);
        float4 g  = *(const float4*)(gamma + c * 8 + q * 4);
        float4 be = *(const float4*)(beta + c * 8 + q * 4);
        bn_affine(sm.x, sq.x, g.x, be.x, S[q * 4 + 0], T[q * 4 + 0]);
        bn_affine(sm.y, sq.y, g.y, be.y, S[q * 4 + 1], T[q * 4 + 1]);
        bn_affine(sm.z, sq.z, g.z, be.z, S[q * 4 + 2], T[q * 4 + 2]);
        bn_affine(sm.w, sq.w, g.w, be.w, S[q * 4 + 3], T[q * 4 + 3]);
    }
    float hv[8];
    hv[0] = h0.x + fmaxf(fmaf(a0.x, S[0], T[0]), 0.f);
    hv[1] = h0.y + fmaxf(fmaf(a0.y, S[1], T[1]), 0.f);
    hv[2] = h0.z + fmaxf(fmaf(a0.z, S[2], T[2]), 0.f);
    hv[3] = h0.w + fmaxf(fmaf(a0.w, S[3], T[3]), 0.f);
    hv[4] = h1.x + fmaxf(fmaf(a1.x, S[4], T[4]), 0.f);
    hv[5] = h1.y + fmaxf(fmaf(a1.y, S[5], T[5]), 0.f);
    hv[6] = h1.z + fmaxf(fmaf(a1.z, S[6], T[6]), 0.f);
    hv[7] = h1.w + fmaxf(fmaf(a1.w, S[7], T[7]), 0.f);
    float p[10];
#pragma unroll
    for (int cls = 0; cls < 10; ++cls) {
        float4 w0 = *(const float4*)&Wt[cls][c * 8];
        float4 w1 = *(const float4*)&Wt[cls][c * 8 + 4];
        float sacc = fmaf(hv[0], w0.x, fmaf(hv[1], w0.y, fmaf(hv[2], w0.z, hv[3] * w0.w)));
        sacc = fmaf(hv[4], w1.x, fmaf(hv[5], w1.y, fmaf(hv[6], w1.z, fmaf(hv[7], w1.w, sacc))));
        p[cls] = sacc;
    }
#pragma unroll
    for (int m = 1; m < 16; m <<= 1)
#pragma unroll
        for (int cls = 0; cls < 10; ++cls)
            p[cls] += __shfl_xor(p[cls], m);
    if (c == 0) {
        if (flags[0]) {
            float* o = (float*)out;
            for (int cls = 0; cls < 10; ++cls) o[node * 10 + cls] = p[cls] + bm[cls];
        } else {
            __hip_bfloat16* o = (__hip_bfloat16*)out;
            for (int cls = 0; cls < 10; ++cls)
                o[node * 10 + cls] = __float2bfloat16(p[cls] + bm[cls]);
        }
    }
}

// ---------------- orchestration ----------------

extern "C" void kernel_launch(void* const* d_in, const int* in_sizes, int n_in,
                              void* d_out, int out_size, void* d_ws, size_t ws_size,
                              hipStream_t stream) {
    const void* h_in = d_in[0];
    const void* ei   = d_in[1];
    const void* Wemb = d_in[3];
    const void* bemb = d_in[4];
    const void* Ws   = d_in[5];
    const void* bs   = d_in[6];
    const void* gam  = d_in[7];
    const void* bet  = d_in[8];
    const void* Wm   = d_in[9];
    const void* bm   = d_in[10];

    char* ws = (char*)d_ws;
    size_t off = 0;
    auto alloc = [&](size_t bytes) -> void* {
        void* p = ws + off;
        off = (off + bytes + 255) & ~(size_t)255;
        return p;
    };
    // contiguous zero-region: counts + stats8 + scanflag + barriers (one memset)
    int* counts    = (int*)alloc((size_t)(NN + 1024) * 4);
    float* stats8  = (float*)alloc((size_t)4 * 8 * 256 * 4);        // per-layer 8-replica stats
    int* scanflag  = (int*)alloc(256);
    int* bar       = (int*)alloc((size_t)4 * 9 * 16 * 4);           // 4 layers x 9 strided ctrs
    size_t zspan   = (size_t)((char*)bar + 4 * 9 * 16 * 4 - (char*)counts);
    float* hbuf    = (float*)alloc((size_t)NN * 128 * 4);
    float* abuf    = (float*)alloc((size_t)NN * 128 * 4);           // fallback path only
    unsigned int* xb = (unsigned int*)alloc((size_t)NN * 64 * 4);   // bf16 x, 256 B/row
    int* offsets   = (int*)alloc((size_t)(NN + 1024) * 4);
    int* bsums     = (int*)alloc(64 * 4);
    float* dinv    = (float*)alloc((size_t)NN * 4);
    uint2* csrw    = (uint2*)alloc((size_t)(EE + NN + 64) * 8);
    int* srcs      = (int*)alloc((size_t)EE * 4);
    int* dsts      = (int*)alloc((size_t)EE * 4);
    int* rank      = (int*)alloc((size_t)EE * 4);
    int* flags     = (int*)alloc(64);
    float* bemb_f  = (float*)alloc(128 * 4);
    float* bs_f    = (float*)alloc(512 * 4);
    float* gam_f   = (float*)alloc(512 * 4);
    float* bet_f   = (float*)alloc(512 * 4);
    float* Wm_f    = (float*)alloc(1280 * 4);
    float* bm_f    = (float*)alloc(16 * 4);
    __bf16* Bhi    = (__bf16*)alloc((size_t)5 * 16384 * 2);
    __bf16* Blo    = (__bf16*)alloc((size_t)5 * 16384 * 2);

    hipMemsetAsync(counts, 0, zspan, stream);   // counts + stats + scan flag + barriers

    int eblocks = (EE + 255) / 256;  // 3125
    k_setup<<<332 + eblocks, 256, 0, stream>>>(h_in, ei, Wemb, Ws, bemb, bs, gam, bet,
                                               Wm, bm, bemb_f, bs_f, gam_f, bet_f, Wm_f,
                                               bm_f, Bhi, Blo, counts, srcs, dsts, rank,
                                               flags);
    int nb = (NN + 1023) / 1024;  // 49
    k_scan<<<nb, 256, 0, stream>>>(counts, offsets, bsums, scanflag, dinv, csrw);
    k_fillemb<<<EMBBLK + eblocks, 256, 0, stream>>>(h_in, Bhi, Blo, bemb_f, hbuf,
                                                    (unsigned short*)xb, flags,
                                                    srcs, dsts, rank, offsets, dinv, csrw);

    // fused (device-barrier) path only if all LBLK blocks provably co-resident
    int fused = 0;
    {
        int maxb = 0, ncu = 0, dev = 0;
        if (hipGetDevice(&dev) == hipSuccess &&
            hipDeviceGetAttribute(&ncu, hipDeviceAttributeMultiprocessorCount, dev) == hipSuccess &&
            hipOccupancyMaxActiveBlocksPerMultiprocessor(&maxb, k_layer, 256, 0) == hipSuccess)
            fused = ((long long)maxb * ncu >= LBLK);
    }

    if (fused) {
        for (int l = 0; l < NL; ++l) {
            k_layer<<<LBLK, 256, 0, stream>>>(xb, csrw, offsets, counts,
                                              bs_f + l * 128, stats8 + (size_t)l * 2048,
                                              gam_f + l * 128, bet_f + l * 128, hbuf,
                                              Bhi + (size_t)(2 + l) * 16384,
                                              Blo + (size_t)(2 + l) * 16384,
                                              (unsigned short*)xb, Wm_f, bm_f, d_out,
                                              flags, (l == 3) ? 1 : 0, bar + l * 144);
        }
    } else {
        int gblocks = (NN + 63) / 64;  // 782
        for (int l = 0; l < NL; ++l) {
            k_agg<<<NN / 4, 256, 0, stream>>>(xb, csrw, offsets, counts,
                                              bs_f + l * 128, abuf,
                                              stats8 + (size_t)l * 2048);
            if (l < 3) {
                k_gemm_layer<<<gblocks, 256, 0, stream>>>(hbuf, abuf,
                                                          stats8 + (size_t)l * 2048,
                                                          gam_f + l * 128, bet_f + l * 128,
                                                          Bhi + (size_t)(2 + l) * 16384,
                                                          Blo + (size_t)(2 + l) * 16384,
                                                          (unsigned short*)xb, hbuf, NN);
            }
        }
        k_mlp_fused<<<NN / 16, 256, 0, stream>>>(hbuf, abuf, stats8 + (size_t)3 * 2048,
                                                 gam_f + 3 * 128, bet_f + 3 * 128,
                                                 Wm_f, bm_f, d_out, flags);
    }
}

// Round 10
// 423.831 us; speedup vs baseline: 1.0955x; 1.0955x over previous
//
#include <hip/hip_runtime.h>
#include <hip/hip_bf16.h>

#define NN 50000
#define EE 800000
#define HIDD 128
#define NL 4
#define NC 10
#define BN_EPS 1e-5f
#define EMBBLK 782   // emb blocks inside k_fillemb

typedef __bf16 bf16x8 __attribute__((ext_vector_type(8)));
typedef float f32x4 __attribute__((ext_vector_type(4)));

__device__ __forceinline__ float bf_lo(unsigned int u) { return __uint_as_float(u << 16); }
__device__ __forceinline__ float bf_hi(unsigned int u) { return __uint_as_float(u & 0xFFFF0000u); }

__device__ __forceinline__ int edge_at(const void* ei, int i64, long long idx) {
    return i64 ? (int)((const long long*)ei)[idx] : ((const int*)ei)[idx];
}

__device__ __forceinline__ float flt_at(const void* p, int fp32, size_t idx) {
    return fp32 ? ((const float*)p)[idx] : (float)((const __hip_bfloat16*)p)[idx];
}

// ---------------- setup: detect flags + convert small arrays + pack B + edge pass ----------------
__global__ __launch_bounds__(256) void k_setup(const void* h, const void* ei,
        const void* Wemb, const void* Ws,
        const void* bemb, const void* bs, const void* gam, const void* bet,
        const void* Wm, const void* bm,
        float* bemb_f, float* bs_f, float* gam_f, float* bet_f, float* Wm_f, float* bm_f,
        __bf16* Bhi, __bf16* Blo, int* counts, int* srcs, int* dsts, int* rank,
        int* flags) {
    int b = blockIdx.x, tid = threadIdx.x;
    if (b >= 332) {  // edge pass: self-detect i64, convert, count, record rank
        __shared__ int zeros;
        if (tid == 0) zeros = 0;
        __syncthreads();
        const int* ii = (const int*)ei;
        int lz = 0;
        for (int i = tid; i < 512; i += 256)
            if (ii[2 * i + 1] == 0) lz++;
        if (lz) atomicAdd(&zeros, lz);
        __syncthreads();
        int i64 = (zeros > 256) ? 1 : 0;
        int e = (b - 332) * 256 + tid;
        if (e < EE) {
            int s = edge_at(ei, i64, e);
            int d = edge_at(ei, i64, (long long)EE + e);
            srcs[e] = s;
            dsts[e] = d;
            if ((unsigned)d < NN) rank[e] = atomicAdd(&counts[d], 1);
        }
        return;
    }
    __shared__ int wild, zeros;
    if (tid == 0) { wild = 0; zeros = 0; }
    __syncthreads();
    const unsigned short* hb = (const unsigned short*)h;
    int lw = 0;
    for (int i = tid; i < 4096; i += 256) {
        unsigned short u = hb[i];
        int e = (u >> 7) & 0xFF;
        if ((e >= 0x8F || e == 0) && (u & 0x7FFF) != 0) lw++;
    }
    if (lw) atomicAdd(&wild, lw);
    const int* ii = (const int*)ei;
    int lz = 0;
    for (int i = tid; i < 512; i += 256)
        if (ii[2 * i + 1] == 0) lz++;
    if (lz) atomicAdd(&zeros, lz);
    __syncthreads();
    int fp32 = (wild > 256) ? 1 : 0;
    int i64  = (zeros > 256) ? 1 : 0;
    if (b == 0 && tid == 0) { flags[0] = fp32; flags[1] = i64; }
    if (b < 320) {  // pack 5 weight matrices into MFMA B-fragment order, hi/lo planes
        int idx = b * 256 + tid;  // < 81920
        int m = idx >> 14, r = idx & 16383;
        int kt = r >> 12, nt = (r >> 9) & 7, lane = (r >> 3) & 63, j = r & 7;
        int k = kt * 32 + (lane >> 4) * 8 + j;
        int n = nt * 16 + (lane & 15);
        float w = (m == 0) ? flt_at(Wemb, fp32, (size_t)k * 128 + n)
                           : flt_at(Ws, fp32, (size_t)(m - 1) * 16384 + (size_t)k * 128 + n);
        __bf16 hi = (__bf16)w;
        Bhi[idx] = hi;
        Blo[idx] = (__bf16)(w - (float)hi);
    } else {
        int i = (b - 320) * 256 + tid;
        const void* src; float* dst; int off2;
        if (i < 128)       { src = bemb; dst = bemb_f; off2 = i; }
        else if (i < 640)  { src = bs;   dst = bs_f;   off2 = i - 128; }
        else if (i < 1152) { src = gam;  dst = gam_f;  off2 = i - 640; }
        else if (i < 1664) { src = bet;  dst = bet_f;  off2 = i - 1152; }
        else if (i < 2944) { src = Wm;   dst = Wm_f;   off2 = i - 1664; }
        else if (i < 2954) { src = bm;   dst = bm_f;   off2 = i - 2944; }
        else return;
        dst[off2] = flt_at(src, fp32, off2);
    }
}

// ---------------- merged scan: per-block prefix + co-resident handoff + finalize ----------------
__global__ __launch_bounds__(256) void k_scan(const int* counts, int* offsets, int* bsums,
                                              int* flag, float* dinv, uint2* csrw) {
    __shared__ int sc[256];
    __shared__ int sadd;
    int tid = threadIdx.x;
    int base = blockIdx.x * 1024 + tid * 4;
    int4 d = {0, 0, 0, 0};
    if (base + 3 < NN) {
        int4 c = *(const int4*)(counts + base);
        d.x = c.x + 1; d.y = c.y + 1; d.z = c.z + 1; d.w = c.w + 1;
    } else {
        if (base + 0 < NN) d.x = counts[base] + 1;
        if (base + 1 < NN) d.y = counts[base + 1] + 1;
        if (base + 2 < NN) d.z = counts[base + 2] + 1;
        if (base + 3 < NN) d.w = counts[base + 3] + 1;
    }
    int s = d.x + d.y + d.z + d.w;
    sc[tid] = s;
    __syncthreads();
    for (int off = 1; off < 256; off <<= 1) {
        int v = (tid >= off) ? sc[tid - off] : 0;
        __syncthreads();
        sc[tid] += v;
        __syncthreads();
    }
    int excl = sc[tid] - s;
    if (tid == 255) {
        bsums[blockIdx.x] = sc[255];
        __threadfence();
        __hip_atomic_fetch_add(flag, 1, __ATOMIC_RELEASE, __HIP_MEMORY_SCOPE_AGENT);
    }
    if (tid == 0) {
        long long g = 0;
        while (__hip_atomic_load(flag, __ATOMIC_ACQUIRE, __HIP_MEMORY_SCOPE_AGENT)
               < (int)gridDim.x) {
            __builtin_amdgcn_s_sleep(1);
            if (++g > (1LL << 30)) break;
        }
        int a = 0;
        for (int i = 0; i < (int)blockIdx.x; ++i)
            a += __hip_atomic_load(&bsums[i], __ATOMIC_RELAXED, __HIP_MEMORY_SCOPE_AGENT);
        sadd = a;
    }
    __syncthreads();
    int add = sadd;
    if (base >= NN) return;
    int4 o;
    o.x = excl + add; o.y = o.x + d.x; o.z = o.y + d.y; o.w = o.z + d.z;
    *(int4*)(offsets + base) = o;
    int ov[4] = {o.x, o.y, o.z, o.w};
    int dd[4] = {d.x, d.y, d.z, d.w};
#pragma unroll
    for (int t = 0; t < 4; ++t) {
        int i = base + t;
        if (i < NN) {
            int c = dd[t] - 1;
            float dv = rsqrtf((float)(c + 1));
            dinv[i] = dv;
            csrw[ov[t] + c] = make_uint2((unsigned)i, __float_as_uint(dv * dv));
        }
    }
}

// ---------------- BN affine helpers ----------------
__device__ __forceinline__ void bn_affine(float sm, float sq, float g, float be,
                                          float& S, float& T) {
    float mu = sm * (1.f / NN);
    float var = fmaxf(sq * (1.f / NN) - mu * mu, 0.f);
    S = rsqrtf(var + BN_EPS) * g;
    T = be - mu * S;
}

__device__ __forceinline__ void sum_reps(const float* ST, int cb, float4& sm, float4& sq) {
    sm = make_float4(0.f, 0.f, 0.f, 0.f);
    sq = make_float4(0.f, 0.f, 0.f, 0.f);
#pragma unroll
    for (int rr = 0; rr < 8; ++rr) {
        float4 a = *(const float4*)(ST + rr * 256 + cb);
        float4 b = *(const float4*)(ST + rr * 256 + 128 + cb);
        sm.x += a.x; sm.y += a.y; sm.z += a.z; sm.w += a.w;
        sq.x += b.x; sq.y += b.y; sq.z += b.z; sq.w += b.w;
    }
}

// ---------------- shared MFMA core (64x128 A-tile, 128x128 B, hi/lo split) ----------------
__device__ __forceinline__ void mfma128(const __bf16 a_hi[][136], const __bf16 a_lo[][136],
                                        const __bf16* __restrict__ Bhi,
                                        const __bf16* __restrict__ Blo,
                                        int lane, int rw, int quad, int l15, f32x4* acc) {
#pragma unroll
    for (int nt = 0; nt < 8; ++nt) acc[nt] = (f32x4){0.f, 0.f, 0.f, 0.f};
#pragma unroll
    for (int kt = 0; kt < 4; ++kt) {
        int k0 = kt * 32 + quad * 8;
        bf16x8 ah = *(const bf16x8*)&a_hi[rw + l15][k0];
        bf16x8 al = *(const bf16x8*)&a_lo[rw + l15][k0];
#pragma unroll
        for (int nt = 0; nt < 8; ++nt) {
            size_t boff = (((size_t)(kt * 8 + nt) * 64 + lane) * 8);
            bf16x8 bh = *(const bf16x8*)(Bhi + boff);
            bf16x8 bl = *(const bf16x8*)(Blo + boff);
            acc[nt] = __builtin_amdgcn_mfma_f32_16x16x32_bf16(ah, bh, acc[nt], 0, 0, 0);
            acc[nt] = __builtin_amdgcn_mfma_f32_16x16x32_bf16(al, bh, acc[nt], 0, 0, 0);
            acc[nt] = __builtin_amdgcn_mfma_f32_16x16x32_bf16(ah, bl, acc[nt], 0, 0, 0);
        }
    }
}

__device__ __forceinline__ void stage_acc(float Cs[][132], const f32x4* acc,
                                          int rw, int quad, int l15) {
#pragma unroll
    for (int nt = 0; nt < 8; ++nt) {
        int col = nt * 16 + l15;
#pragma unroll
        for (int reg = 0; reg < 4; ++reg)
            Cs[rw + quad * 4 + reg][col] = acc[nt][reg];
    }
}

// ---------------- merged fill + embedding GEMM ----------------
__global__ __launch_bounds__(256) void k_fillemb(const void* __restrict__ Araw,
        const __bf16* __restrict__ Bhi, const __bf16* __restrict__ Blo,
        const float* __restrict__ bias, float* __restrict__ C,
        unsigned short* __restrict__ Cb, const int* __restrict__ flags,
        const int* __restrict__ srcs, const int* __restrict__ dsts,
        const int* __restrict__ rank, const int* __restrict__ offsets,
        const float* __restrict__ dinv, uint2* __restrict__ csrw) {
    int tid = threadIdx.x;
    if (blockIdx.x >= EMBBLK) {   // ---- fill part ----
        int e = (blockIdx.x - EMBBLK) * 256 + tid;
        if (e >= EE) return;
        int d = dsts[e];
        if ((unsigned)d >= NN) return;
        int s = srcs[e];
        if ((unsigned)s >= NN) s = d;
        int r = rank[e];
        float w = dinv[s] * dinv[d];
        csrw[offsets[d] + r] = make_uint2((unsigned)s, __float_as_uint(w));
        return;
    }
    __shared__ __align__(16) char smem[2 * 64 * 136 * 2];
    __bf16 (*a_hi)[136] = (__bf16(*)[136])smem;
    __bf16 (*a_lo)[136] = (__bf16(*)[136])(smem + 64 * 136 * 2);
    float (*Cs)[132] = (float(*)[132])smem;
    int r0 = blockIdx.x * 64;
    int cq = tid & 31, rb = tid >> 5, cb4 = cq * 4;
    int afp32 = flags[0];
#pragma unroll
    for (int p = 0; p < 8; ++p) {
        int r = rb + p * 8;
        int gr = r0 + r;
        float f[4] = {0.f, 0.f, 0.f, 0.f};
        if (gr < NN) {
            if (afp32) {
                float4 v = ((const float4*)Araw)[(size_t)gr * 32 + cq];
                f[0] = v.x; f[1] = v.y; f[2] = v.z; f[3] = v.w;
            } else {
                const __hip_bfloat16* ab = (const __hip_bfloat16*)Araw + (size_t)gr * 128 + cb4;
#pragma unroll
                for (int t = 0; t < 4; ++t) f[t] = (float)ab[t];
            }
        }
        union { __bf16 b[4]; ushort4 u; } ph, pl;
#pragma unroll
        for (int t = 0; t < 4; ++t) {
            __bf16 hi = (__bf16)f[t];
            ph.b[t] = hi;
            pl.b[t] = (__bf16)(f[t] - (float)hi);
        }
        *(ushort4*)&a_hi[r][cb4] = ph.u;
        *(ushort4*)&a_lo[r][cb4] = pl.u;
    }
    __syncthreads();
    int lane = tid & 63, wave = tid >> 6, quad = lane >> 4, l15 = lane & 15, rw = wave * 16;
    f32x4 acc[8];
    mfma128(a_hi, a_lo, Bhi, Blo, lane, rw, quad, l15, acc);     // W_emb
    __syncthreads();
    stage_acc(Cs, acc, rw, quad, l15);
    __syncthreads();
    int colc = (tid & 15) * 8;
    float4 b0v = *(const float4*)(bias + colc);
    float4 b1v = *(const float4*)(bias + colc + 4);
    float v[4][8];
#pragma unroll
    for (int p = 0; p < 4; ++p) {
        int row = (tid >> 4) + p * 16;
        *(float4*)&v[p][0] = *(const float4*)&Cs[row][colc];
        *(float4*)&v[p][4] = *(const float4*)&Cs[row][colc + 4];
        v[p][0] += b0v.x; v[p][1] += b0v.y; v[p][2] += b0v.z; v[p][3] += b0v.w;
        v[p][4] += b1v.x; v[p][5] += b1v.y; v[p][6] += b1v.z; v[p][7] += b1v.w;
        int gr = r0 + row;
        if (gr < NN) {
            float* cr = C + (size_t)gr * 128 + colc;
            *(float4*)cr = *(float4*)&v[p][0];
            *(float4*)(cr + 4) = *(float4*)&v[p][4];
        }
    }
    __syncthreads();
#pragma unroll
    for (int p = 0; p < 4; ++p) {
        int row = (tid >> 4) + p * 16;
        union { __bf16 b[8]; uint4 u; } ph, pl;
#pragma unroll
        for (int t = 0; t < 8; ++t) {
            float x = v[p][t];
            __bf16 hi = (__bf16)x;
            ph.b[t] = hi;
            pl.b[t] = (__bf16)(x - (float)hi);
        }
        *(uint4*)&a_hi[row][colc] = ph.u;
        *(uint4*)&a_lo[row][colc] = pl.u;
    }
    __syncthreads();
    mfma128(a_hi, a_lo, Bhi + 16384, Blo + 16384, lane, rw, quad, l15, acc);  // W_0
    __syncthreads();
    stage_acc(Cs, acc, rw, quad, l15);
    __syncthreads();
#pragma unroll
    for (int p = 0; p < 4; ++p) {
        int row = (tid >> 4) + p * 16;
        int gr = r0 + row;
        if (gr >= NN) continue;
        float w[8];
        *(float4*)&w[0] = *(const float4*)&Cs[row][colc];
        *(float4*)&w[4] = *(const float4*)&Cs[row][colc + 4];
        union { unsigned short us[8]; uint4 u4; } pk;
#pragma unroll
        for (int t = 0; t < 8; ++t)
            pk.us[t] = __bfloat16_as_ushort(__float2bfloat16(w[t]));
        *(uint4*)(Cb + (size_t)gr * 128 + colc) = pk.u4;
    }
}

// ---------------- aggregation with fused BN statistics (round-3 verbatim, 430 us config) ----------------
// 8 nodes/block (wave handles 2 nodes). Records (src, weight) preloaded for both nodes
// up front; 4-deep gather unroll for ILP. No dinv in the hot loop.
#define FMA8(A, U, W) \
    A[0] = fmaf(bf_lo(U.x), W, A[0]); A[1] = fmaf(bf_hi(U.x), W, A[1]); \
    A[2] = fmaf(bf_lo(U.y), W, A[2]); A[3] = fmaf(bf_hi(U.y), W, A[3]); \
    A[4] = fmaf(bf_lo(U.z), W, A[4]); A[5] = fmaf(bf_hi(U.z), W, A[5]); \
    A[6] = fmaf(bf_lo(U.w), W, A[6]); A[7] = fmaf(bf_hi(U.w), W, A[7]);

__global__ __launch_bounds__(256) void k_agg(const unsigned int* __restrict__ xb,
                                             const uint2* __restrict__ csrw,
                                             const int* __restrict__ offsets,
                                             const int* __restrict__ counts,
                                             const float* __restrict__ bias,
                                             float* __restrict__ out,
                                             float* __restrict__ stats) {
    int tid = threadIdx.x;
    int wave = tid >> 6, lane = tid & 63;
    int l15 = lane & 15, quarter = lane >> 4;
    int col = l15 * 8;
    float4 b0 = *(const float4*)(bias + col);
    float4 b1 = *(const float4*)(bias + col + 4);
    float ssm[8] = {0.f, 0.f, 0.f, 0.f, 0.f, 0.f, 0.f, 0.f};
    float ssq[8] = {0.f, 0.f, 0.f, 0.f, 0.f, 0.f, 0.f, 0.f};
    // metadata + first record block for both nodes, issued up front
    int n0 = blockIdx.x * 8 + wave;
    int n1 = n0 + 4;
    int st[2], cn[2];
    st[0] = offsets[n0]; cn[0] = counts[n0] + 1;
    st[1] = offsets[n1]; cn[1] = counts[n1] + 1;
    uint2 rec[2];
    rec[0] = make_uint2(0u, 0u);
    rec[1] = make_uint2(0u, 0u);
    if (lane < cn[0]) rec[0] = csrw[st[0] + lane];
    if (lane < cn[1]) rec[1] = csrw[st[1] + lane];
#pragma unroll
    for (int p = 0; p < 2; ++p) {
        int node = (p == 0) ? n0 : n1;
        int start = st[p], cnt = cn[p];
        int sidx = (int)rec[p].x;
        float wl = __uint_as_float(rec[p].y);
        float a0[8] = {0.f, 0.f, 0.f, 0.f, 0.f, 0.f, 0.f, 0.f};
        float a1[8] = {0.f, 0.f, 0.f, 0.f, 0.f, 0.f, 0.f, 0.f};
        float a2[8] = {0.f, 0.f, 0.f, 0.f, 0.f, 0.f, 0.f, 0.f};
        float a3[8] = {0.f, 0.f, 0.f, 0.f, 0.f, 0.f, 0.f, 0.f};
        int base = 0;
        for (;;) {
            int m = min(64, cnt - base);
            int j = 0;
            for (; j + 12 < m; j += 16) {   // 4 gathers in flight (16 edges)
                int e0 = j + quarter, e1 = j + 4 + quarter;
                int e2 = j + 8 + quarter, e3 = j + 12 + quarter;
                int s0 = __shfl(sidx, e0); float w0 = __shfl(wl, e0);
                int s1 = __shfl(sidx, e1); float w1 = __shfl(wl, e1);
                int s2 = __shfl(sidx, e2); float w2 = __shfl(wl, e2);
                int s3 = __shfl(sidx, e3); float w3 = __shfl(wl, e3);
                uint4 u0 = *((const uint4*)(xb + (size_t)s0 * 64) + l15);
                uint4 u1 = *((const uint4*)(xb + (size_t)s1 * 64) + l15);
                uint4 u2 = *((const uint4*)(xb + (size_t)s2 * 64) + l15);
                uint4 u3 = *((const uint4*)(xb + (size_t)s3 * 64) + l15);
                FMA8(a0, u0, w0);
                FMA8(a1, u1, w1);
                FMA8(a2, u2, w2);
                FMA8(a3, u3, w3);
            }
            for (; j < m; j += 4) {         // masked tail (w=0 beyond cnt)
                int e0 = j + quarter;
                int s0 = __shfl(sidx, e0); float w0 = __shfl(wl, e0);
                uint4 u0 = *((const uint4*)(xb + (size_t)s0 * 64) + l15);
                FMA8(a0, u0, w0);
            }
            base += 64;
            if (base >= cnt) break;
            uint2 r = make_uint2(0u, 0u);
            if (base + lane < cnt) r = csrw[start + base + lane];
            sidx = (int)r.x;
            wl = __uint_as_float(r.y);
        }
#pragma unroll
        for (int k = 0; k < 8; ++k) {
            float a = (a0[k] + a1[k]) + (a2[k] + a3[k]);
            a += __shfl_xor(a, 16);
            a += __shfl_xor(a, 32);
            a0[k] = a;
        }
        if (quarter == 0) {
            float o[8];
            o[0] = a0[0] + b0.x; o[1] = a0[1] + b0.y;
            o[2] = a0[2] + b0.z; o[3] = a0[3] + b0.w;
            o[4] = a0[4] + b1.x; o[5] = a0[5] + b1.y;
            o[6] = a0[6] + b1.z; o[7] = a0[7] + b1.w;
            float* orow = out + (size_t)node * 128 + col;
            *(float4*)orow = *(float4*)&o[0];
            *(float4*)(orow + 4) = *(float4*)&o[4];
#pragma unroll
            for (int k = 0; k < 8; ++k) {
                ssm[k] += o[k];
                ssq[k] = fmaf(o[k], o[k], ssq[k]);
            }
        }
    }
    __shared__ float red[4][256];
    if (quarter == 0) {
#pragma unroll
        for (int k = 0; k < 8; ++k) {
            red[wave][col + k] = ssm[k];
            red[wave][128 + col + k] = ssq[k];
        }
    }
    __syncthreads();
    float v = red[0][tid] + red[1][tid] + red[2][tid] + red[3][tid];
    atomicAdd(&stats[(blockIdx.x & 7) * 256 + tid], v);
}

// ---------------- per-layer GEMM: A-row = hbuf + relu(BN(abuf)); writes h' and bf16 x ----------------
__global__ __launch_bounds__(256) void k_gemm_layer(const float* __restrict__ Ah,
                                                    const float* __restrict__ Aagg,
                                                    const float* __restrict__ ST,
                                                    const float* __restrict__ gamma,
                                                    const float* __restrict__ beta,
                                                    const __bf16* __restrict__ Bhi,
                                                    const __bf16* __restrict__ Blo,
                                                    unsigned short* __restrict__ Cb,
                                                    float* __restrict__ Hout, int M) {
    __shared__ __align__(16) char smem[2 * 64 * 136 * 2];
    __bf16 (*a_hi)[136] = (__bf16(*)[136])smem;
    __bf16 (*a_lo)[136] = (__bf16(*)[136])(smem + 64 * 136 * 2);
    float (*Cs)[132] = (float(*)[132])smem;
    int tid = threadIdx.x;
    int r0 = blockIdx.x * 64;
    int cq = tid & 31, rb = tid >> 5, cb4 = cq * 4;
    float4 S4, T4;
    {
        float4 sm, sq;
        sum_reps(ST, cb4, sm, sq);
        float4 g  = *(const float4*)(gamma + cb4);
        float4 be = *(const float4*)(beta + cb4);
        bn_affine(sm.x, sq.x, g.x, be.x, S4.x, T4.x);
        bn_affine(sm.y, sq.y, g.y, be.y, S4.y, T4.y);
        bn_affine(sm.z, sq.z, g.z, be.z, S4.z, T4.z);
        bn_affine(sm.w, sq.w, g.w, be.w, S4.w, T4.w);
    }
#pragma unroll
    for (int p = 0; p < 8; ++p) {
        int r = rb + p * 8;
        int gr = r0 + r;
        float f[4] = {0.f, 0.f, 0.f, 0.f};
        if (gr < M) {
            float4 v = *(const float4*)(Ah + (size_t)gr * 128 + cb4);
            float4 a = *(const float4*)(Aagg + (size_t)gr * 128 + cb4);
            v.x += fmaxf(fmaf(a.x, S4.x, T4.x), 0.f);
            v.y += fmaxf(fmaf(a.y, S4.y, T4.y), 0.f);
            v.z += fmaxf(fmaf(a.z, S4.z, T4.z), 0.f);
            v.w += fmaxf(fmaf(a.w, S4.w, T4.w), 0.f);
            *(float4*)(Hout + (size_t)gr * 128 + cb4) = v;
            f[0] = v.x; f[1] = v.y; f[2] = v.z; f[3] = v.w;
        }
        union { __bf16 b[4]; ushort4 u; } ph, pl;
#pragma unroll
        for (int t = 0; t < 4; ++t) {
            __bf16 hi = (__bf16)f[t];
            ph.b[t] = hi;
            pl.b[t] = (__bf16)(f[t] - (float)hi);
        }
        *(ushort4*)&a_hi[r][cb4] = ph.u;
        *(ushort4*)&a_lo[r][cb4] = pl.u;
    }
    __syncthreads();
    int lane = tid & 63, wave = tid >> 6, quad = lane >> 4, l15 = lane & 15, rw = wave * 16;
    f32x4 acc[8];
    mfma128(a_hi, a_lo, Bhi, Blo, lane, rw, quad, l15, acc);
    __syncthreads();
    stage_acc(Cs, acc, rw, quad, l15);
    __syncthreads();
    int colc = (tid & 15) * 8;
#pragma unroll
    for (int p = 0; p < 4; ++p) {
        int row = (tid >> 4) + p * 16;
        int gr = r0 + row;
        if (gr >= M) continue;
        float w[8];
        *(float4*)&w[0] = *(const float4*)&Cs[row][colc];
        *(float4*)&w[4] = *(const float4*)&Cs[row][colc + 4];
        union { unsigned short us[8]; uint4 u4; } pk;
#pragma unroll
        for (int t = 0; t < 8; ++t)
            pk.us[t] = __bfloat16_as_ushort(__float2bfloat16(w[t]));
        *(uint4*)(Cb + (size_t)gr * 128 + colc) = pk.u4;
    }
}

// ---------------- fused final BN + MLP ----------------
__global__ __launch_bounds__(256) void k_mlp_fused(const float* __restrict__ h,
                                                   const float* __restrict__ agg,
                                                   const float* __restrict__ ST,
                                                   const float* __restrict__ gamma,
                                                   const float* __restrict__ beta,
                                                   const float* __restrict__ Wm,
                                                   const float* __restrict__ bm,
                                                   void* __restrict__ out,
                                                   const int* __restrict__ flags) {
    __shared__ float Wt[10][132];
    int tid = threadIdx.x;
    for (int i = tid; i < 1280; i += 256) {
        int cls = i >> 7, k = i & 127;
        Wt[cls][k] = Wm[k * 10 + cls];
    }
    __syncthreads();
    int wave = tid >> 6, lane = tid & 63;
    int nl = lane >> 4, c = lane & 15;
    int node = blockIdx.x * 16 + wave * 4 + nl;
    size_t rowo = (size_t)node * 128 + c * 8;
    float4 h0 = *(const float4*)(h + rowo);
    float4 h1 = *(const float4*)(h + rowo + 4);
    float4 a0 = *(const float4*)(agg + rowo);
    float4 a1 = *(const float4*)(agg + rowo + 4);
    float S[8], T[8];
#pragma unroll
    for (int q = 0; q < 2; ++q) {
        float4 sm, sq;
        sum_reps(ST, c * 8 + q * 4, sm, sq);
        float4 g  = *(const float4*)(gamma + c * 8 + q * 4);
        float4 be = *(const float4*)(beta + c * 8 + q * 4);
        bn_affine(sm.x, sq.x, g.x, be.x, S[q * 4 + 0], T[q * 4 + 0]);
        bn_affine(sm.y, sq.y, g.y, be.y, S[q * 4 + 1], T[q * 4 + 1]);
        bn_affine(sm.z, sq.z, g.z, be.z, S[q * 4 + 2], T[q * 4 + 2]);
        bn_affine(sm.w, sq.w, g.w, be.w, S[q * 4 + 3], T[q * 4 + 3]);
    }
    float hv[8];
    hv[0] = h0.x + fmaxf(fmaf(a0.x, S[0], T[0]), 0.f);
    hv[1] = h0.y + fmaxf(fmaf(a0.y, S[1], T[1]), 0.f);
    hv[2] = h0.z + fmaxf(fmaf(a0.z, S[2], T[2]), 0.f);
    hv[3] = h0.w + fmaxf(fmaf(a0.w, S[3], T[3]), 0.f);
    hv[4] = h1.x + fmaxf(fmaf(a1.x, S[4], T[4]), 0.f);
    hv[5] = h1.y + fmaxf(fmaf(a1.y, S[5], T[5]), 0.f);
    hv[6] = h1.z + fmaxf(fmaf(a1.z, S[6], T[6]), 0.f);
    hv[7] = h1.w + fmaxf(fmaf(a1.w, S[7], T[7]), 0.f);
    float p[10];
#pragma unroll
    for (int cls = 0; cls < 10; ++cls) {
        float4 w0 = *(const float4*)&Wt[cls][c * 8];
        float4 w1 = *(const float4*)&Wt[cls][c * 8 + 4];
        float sacc = fmaf(hv[0], w0.x, fmaf(hv[1], w0.y, fmaf(hv[2], w0.z, hv[3] * w0.w)));
        sacc = fmaf(hv[4], w1.x, fmaf(hv[5], w1.y, fmaf(hv[6], w1.z, fmaf(hv[7], w1.w, sacc))));
        p[cls] = sacc;
    }
#pragma unroll
    for (int m = 1; m < 16; m <<= 1)
#pragma unroll
        for (int cls = 0; cls < 10; ++cls)
            p[cls] += __shfl_xor(p[cls], m);
    if (c == 0) {
        if (flags[0]) {
            float* o = (float*)out;
            for (int cls = 0; cls < 10; ++cls) o[node * 10 + cls] = p[cls] + bm[cls];
        } else {
            __hip_bfloat16* o = (__hip_bfloat16*)out;
            for (int cls = 0; cls < 10; ++cls)
                o[node * 10 + cls] = __float2bfloat16(p[cls] + bm[cls]);
        }
    }
}

// ---------------- orchestration ----------------

extern "C" void kernel_launch(void* const* d_in, const int* in_sizes, int n_in,
                              void* d_out, int out_size, void* d_ws, size_t ws_size,
                              hipStream_t stream) {
    const void* h_in = d_in[0];
    const void* ei   = d_in[1];
    const void* Wemb = d_in[3];
    const void* bemb = d_in[4];
    const void* Ws   = d_in[5];
    const void* bs   = d_in[6];
    const void* gam  = d_in[7];
    const void* bet  = d_in[8];
    const void* Wm   = d_in[9];
    const void* bm   = d_in[10];

    char* ws = (char*)d_ws;
    size_t off = 0;
    auto alloc = [&](size_t bytes) -> void* {
        void* p = ws + off;
        off = (off + bytes + 255) & ~(size_t)255;
        return p;
    };
    // contiguous zero-region: counts + stats8 + scanflag (one memset)
    int* counts    = (int*)alloc((size_t)(NN + 1024) * 4);
    float* stats8  = (float*)alloc((size_t)4 * 8 * 256 * 4);        // per-layer 8-replica stats
    int* scanflag  = (int*)alloc(256);
    size_t zspan   = (size_t)((char*)scanflag + 256 - (char*)counts);
    float* hbuf    = (float*)alloc((size_t)NN * 128 * 4);
    float* abuf    = (float*)alloc((size_t)NN * 128 * 4);
    unsigned int* xb = (unsigned int*)alloc((size_t)NN * 64 * 4);   // bf16 x, 256 B/row
    int* offsets   = (int*)alloc((size_t)(NN + 1024) * 4);
    int* bsums     = (int*)alloc(64 * 4);
    float* dinv    = (float*)alloc((size_t)NN * 4);
    uint2* csrw    = (uint2*)alloc((size_t)(EE + NN + 64) * 8);     // (src, weight) records
    int* srcs      = (int*)alloc((size_t)EE * 4);
    int* dsts      = (int*)alloc((size_t)EE * 4);
    int* rank      = (int*)alloc((size_t)EE * 4);
    int* flags     = (int*)alloc(64);
    float* bemb_f  = (float*)alloc(128 * 4);
    float* bs_f    = (float*)alloc(512 * 4);
    float* gam_f   = (float*)alloc(512 * 4);
    float* bet_f   = (float*)alloc(512 * 4);
    float* Wm_f    = (float*)alloc(1280 * 4);
    float* bm_f    = (float*)alloc(16 * 4);
    __bf16* Bhi    = (__bf16*)alloc((size_t)5 * 16384 * 2);
    __bf16* Blo    = (__bf16*)alloc((size_t)5 * 16384 * 2);

    hipMemsetAsync(counts, 0, zspan, stream);   // counts + stats + scan flag

    int eblocks = (EE + 255) / 256;  // 3125
    k_setup<<<332 + eblocks, 256, 0, stream>>>(h_in, ei, Wemb, Ws, bemb, bs, gam, bet,
                                               Wm, bm, bemb_f, bs_f, gam_f, bet_f, Wm_f,
                                               bm_f, Bhi, Blo, counts, srcs, dsts, rank,
                                               flags);
    int nb = (NN + 1023) / 1024;  // 49
    k_scan<<<nb, 256, 0, stream>>>(counts, offsets, bsums, scanflag, dinv, csrw);
    // merged: emb GEMM (blocks 0..781) + CSR fill (blocks 782..3906)
    k_fillemb<<<EMBBLK + eblocks, 256, 0, stream>>>(h_in, Bhi, Blo, bemb_f, hbuf,
                                                    (unsigned short*)xb, flags,
                                                    srcs, dsts, rank, offsets, dinv, csrw);

    int gblocks = (NN + 63) / 64;  // 782
    for (int l = 0; l < NL; ++l) {
        k_agg<<<NN / 8, 256, 0, stream>>>(xb, csrw, offsets, counts,
                                          bs_f + l * 128, abuf, stats8 + (size_t)l * 2048);
        if (l < 3) {
            k_gemm_layer<<<gblocks, 256, 0, stream>>>(hbuf, abuf, stats8 + (size_t)l * 2048,
                                                      gam_f + l * 128, bet_f + l * 128,
                                                      Bhi + (size_t)(2 + l) * 16384,
                                                      Blo + (size_t)(2 + l) * 16384,
                                                      (unsigned short*)xb, hbuf, NN);
        }
    }
    k_mlp_fused<<<NN / 16, 256, 0, stream>>>(hbuf, abuf, stats8 + (size_t)3 * 2048,
                                             gam_f + 3 * 128, bet_f + 3 * 128,
                                             Wm_f, bm_f, d_out, flags);
}